// Round 1
// baseline (5415.836 us; speedup 1.0000x reference)
//
#include <hip/hip_runtime.h>
#include <math.h>

#define B 64
#define CIN 2
#define CH 32
#define H 128
#define W 128
#define MODES 12
#define KY 24              // kept ky rows: 0..11 and 116..127
#define KX 12              // kept kx cols
#define HW (H*W)           // 16384
#define NMODE (KY*KX)      // 288

__device__ __forceinline__ float gelu_f(float x) {
    return 0.5f * x * (1.0f + erff(x * 0.70710678118654752f));
}

// ---------------- twiddle tables ----------------
// W tables:  [w][k] (for s_load in dft_w)  and [k][w] (per-lane in fused irfft)
// H tables:  [h][ky] (s_load in dft_h)     and [ky][h] (per-lane in idft_h)
__global__ __launch_bounds__(256) void k_init_tables(
        float* cWwk, float* sWwk, float* cWkw, float* sWkw,
        float* cHhk, float* sHhk, float* cHkh, float* sHkh) {
    int t = blockIdx.x * 256 + threadIdx.x;
    const float TWO_PI_OVER = 6.283185307179586476925f / 128.0f;
    if (t < MODES * W) {
        int k = t / W, w = t % W;
        int m = (k * w) & 127;
        float s, c;
        sincosf(TWO_PI_OVER * (float)m, &s, &c);
        cWkw[k * W + w] = c;  sWkw[k * W + w] = s;
        cWwk[w * MODES + k] = c;  sWwk[w * MODES + k] = s;
    } else if (t < MODES * W + KY * H) {
        int u = t - MODES * W;
        int kyI = u / H, hh = u % H;
        int ky = (kyI < MODES) ? kyI : (H - MODES + (kyI - MODES));  // 116..127
        int m = (ky * hh) & 127;
        float s, c;
        sincosf(TWO_PI_OVER * (float)m, &s, &c);
        cHkh[kyI * H + hh] = c;  sHkh[kyI * H + hh] = s;
        cHhk[hh * KY + kyI] = c;  sHhk[hh * KY + kyI] = s;
    }
}

// ---------------- weight reorder: wR[layer][m][i][o]{re,im}, m = kyI*KX+kx ---
__global__ __launch_bounds__(256) void k_reorder_w(
        const float* __restrict__ w1r, const float* __restrict__ w1i,
        const float* __restrict__ w2r, const float* __restrict__ w2i,
        float* __restrict__ wR) {
    int idx = blockIdx.x * 256 + threadIdx.x;   // 4*288*1024
    if (idx >= 4 * NMODE * CH * CH) return;
    int o = idx & 31;
    int i = (idx >> 5) & 31;
    int m = (idx >> 10) % NMODE;
    int layer = idx / (NMODE * CH * CH);
    int kyI = m / KX, kx = m % KX;
    const float *sr, *si;
    int row;
    if (kyI < MODES) { sr = w1r; si = w1i; row = kyI; }
    else             { sr = w2r; si = w2i; row = kyI - MODES; }
    int src = ((layer * CH + i) * CH + o) * (MODES * MODES) + row * MODES + kx;
    wR[(size_t)idx * 2]     = sr[src];
    wR[(size_t)idx * 2 + 1] = si[src];
}

// ---------------- ww transpose: wwT[layer][i][o] = ww[layer][o][i] ----------
__global__ __launch_bounds__(256) void k_transpose_ww(
        const float* __restrict__ ww, float* __restrict__ wwT) {
    int idx = blockIdx.x * 256 + threadIdx.x;
    if (idx >= 4 * CH * CH) return;
    int l = idx / (CH * CH);
    int r = idx % (CH * CH);
    int i = r / CH, o = r % CH;
    wwT[idx] = ww[l * CH * CH + o * CH + i];
}

// ---------------- lifting conv3x3 circular: x[B,2,H,W] -> h[B,32,H,W] -------
__global__ __launch_bounds__(128) void k_lift(
        const float* __restrict__ x, const float* __restrict__ pw,
        const float* __restrict__ pb, float* __restrict__ h) {
    int bh = blockIdx.x;            // b*H + hr
    int b = bh >> 7, hr = bh & 127;
    int w = threadIdx.x;
    int wl = (w + W - 1) & (W - 1), wr2 = (w + 1) & (W - 1);
    float xv[CIN][3][3];
    #pragma unroll
    for (int ic = 0; ic < CIN; ++ic) {
        const float* xc = x + (size_t)(b * CIN + ic) * HW;
        #pragma unroll
        for (int r = 0; r < 3; ++r) {
            int hh = (hr + r - 1 + H) & (H - 1);
            const float* xr = xc + hh * W;
            xv[ic][r][0] = xr[wl];
            xv[ic][r][1] = xr[w];
            xv[ic][r][2] = xr[wr2];
        }
    }
    for (int o = 0; o < CH; ++o) {
        float acc = pb[o];                       // uniform -> s_load
        const float* wo = pw + o * CIN * 9;      // uniform
        #pragma unroll
        for (int ic = 0; ic < CIN; ++ic)
            #pragma unroll
            for (int r = 0; r < 3; ++r)
                #pragma unroll
                for (int c3 = 0; c3 < 3; ++c3)
                    acc += xv[ic][r][c3] * wo[ic * 9 + r * 3 + c3];
        h[(size_t)(b * CH + o) * HW + hr * W + w] = acc;
    }
}

// ---------------- DFT along W: h rows -> Xw[row][k]{re,im}, k=0..11 ---------
// thread = one row; twiddles are loop-uniform -> SGPR; acc in VGPRs.
__global__ __launch_bounds__(256) void k_dft_w(
        const float* __restrict__ h, const float* __restrict__ cWwk,
        const float* __restrict__ sWwk, float* __restrict__ Xw) {
    int row = blockIdx.x * 256 + threadIdx.x;   // < B*CH*H = 262144
    const float* src = h + (size_t)row * W;
    float accr[MODES], acci[MODES];
    #pragma unroll
    for (int k = 0; k < MODES; ++k) { accr[k] = 0.f; acci[k] = 0.f; }
    for (int w4 = 0; w4 < W; w4 += 4) {
        float4 v = *(const float4*)(src + w4);
        #pragma unroll
        for (int j = 0; j < 4; ++j) {
            float xval = (j == 0) ? v.x : (j == 1) ? v.y : (j == 2) ? v.z : v.w;
            int w = w4 + j;
            const float* cw = cWwk + w * MODES;   // uniform -> s_load
            const float* sw = sWwk + w * MODES;
            #pragma unroll
            for (int k = 0; k < MODES; ++k) {
                accr[k] += xval * cw[k];
                acci[k] -= xval * sw[k];
            }
        }
    }
    float2* dst = (float2*)(Xw + (size_t)row * MODES * 2);
    #pragma unroll
    for (int k = 0; k < MODES; ++k) dst[k] = make_float2(accr[k], acci[k]);
}

// ---------------- DFT along H: Xw -> Xf[m][b*CH+c]{re,im} -------------------
// thread = (bc,kx); blockIdx.y selects ky-half so twiddle loads stay uniform.
__global__ __launch_bounds__(256) void k_dft_h(
        const float* __restrict__ Xw, const float* __restrict__ cHhk,
        const float* __restrict__ sHhk, float* __restrict__ Xf) {
    int t = blockIdx.x * 256 + threadIdx.x;     // < B*CH*KX = 24576
    int bc = t / KX, kx = t % KX;
    int kyh = blockIdx.y;                        // 0 or 1 -> ky block of 12
    const float2* src = (const float2*)Xw + (size_t)bc * H * KX + kx;
    float accr[MODES], acci[MODES];
    #pragma unroll
    for (int j = 0; j < MODES; ++j) { accr[j] = 0.f; acci[j] = 0.f; }
    for (int hh = 0; hh < H; ++hh) {
        float2 v = src[hh * KX];
        const float* ch = cHhk + hh * KY + kyh * MODES;  // uniform -> s_load
        const float* sh = sHhk + hh * KY + kyh * MODES;
        #pragma unroll
        for (int j = 0; j < MODES; ++j) {
            float c = ch[j], s = sh[j];
            accr[j] += v.x * c + v.y * s;   // (xr+ixi)(c-is)
            acci[j] += v.y * c - v.x * s;
        }
    }
    float2* dst = (float2*)Xf;
    #pragma unroll
    for (int j = 0; j < MODES; ++j) {
        int m = (kyh * MODES + j) * KX + kx;
        dst[(size_t)m * (B * CH) + bc] = make_float2(accr[j], acci[j]);
    }
}

// ---------------- spectral channel mix: per mode, Y[b,o] = sum_i X[b,i]W[i,o]
__global__ __launch_bounds__(256) void k_specmul(
        const float* __restrict__ Xf, const float* __restrict__ wRl,
        float* __restrict__ Yf) {
    int m = blockIdx.x;                 // 0..287
    int o = threadIdx.x & 31;
    int bq = threadIdx.x >> 5;          // 0..7 -> 8 b's each
    const float2* X  = (const float2*)Xf  + (size_t)m * (B * CH);
    const float2* Wm = (const float2*)wRl + (size_t)m * (CH * CH);
    float accr[8], acci[8];
    #pragma unroll
    for (int j = 0; j < 8; ++j) { accr[j] = 0.f; acci[j] = 0.f; }
    for (int i = 0; i < CH; ++i) {
        float2 wv = Wm[i * CH + o];     // coalesced across lanes
        #pragma unroll
        for (int j = 0; j < 8; ++j) {
            int b = bq * 8 + j;
            float2 xv = X[b * CH + i];  // shared across 32 lanes -> cache bcast
            accr[j] += xv.x * wv.x - xv.y * wv.y;
            acci[j] += xv.x * wv.y + xv.y * wv.x;
        }
    }
    float2* Yp = (float2*)Yf;
    #pragma unroll
    for (int j = 0; j < 8; ++j) {
        int b = bq * 8 + j;
        Yp[((size_t)b * CH + o) * NMODE + m] = make_float2(accr[j], acci[j]);
    }
}

// ---------------- inverse DFT along H: Yf -> Z[b][h][o][kx]{re,im} ----------
// block = (b,o); lane = h; Y reads are block-uniform -> s_load.
__global__ __launch_bounds__(128) void k_idft_h(
        const float* __restrict__ Yf, const float* __restrict__ cHkh,
        const float* __restrict__ sHkh, float* __restrict__ Z) {
    int bo = blockIdx.x;                // b*CH + o
    int b = bo / CH, o = bo % CH;
    int hh = threadIdx.x;
    const float2* Y = (const float2*)Yf + (size_t)bo * NMODE;
    float zr[KX], zi[KX];
    #pragma unroll
    for (int kx = 0; kx < KX; ++kx) { zr[kx] = 0.f; zi[kx] = 0.f; }
    for (int ky = 0; ky < KY; ++ky) {
        float c = cHkh[ky * H + hh];    // per-lane, coalesced
        float s = sHkh[ky * H + hh];
        #pragma unroll
        for (int kx = 0; kx < KX; ++kx) {
            float2 y = Y[ky * KX + kx]; // uniform -> s_load
            zr[kx] += y.x * c - y.y * s;   // (yr+iyi)(c+is)
            zi[kx] += y.x * s + y.y * c;
        }
    }
    float2* dst = (float2*)Z + (((size_t)b * H + hh) * CH + o) * KX;
    #pragma unroll
    for (int kx = 0; kx < KX; ++kx) dst[kx] = make_float2(zr[kx], zi[kx]);
}

// ---------------- fused: pointwise GEMM + irfft(W) + bias + GELU, in-place h
__global__ __launch_bounds__(128) void k_fused(
        float* __restrict__ h, const float* __restrict__ Z,
        const float* __restrict__ wwT, const float* __restrict__ wb,
        const float* __restrict__ cWkw, const float* __restrict__ sWkw) {
    int bh = blockIdx.x;                // b*H + hr
    int b = bh >> 7, hr = bh & 127;
    int w = threadIdx.x;
    float* hbase = h + (size_t)b * CH * HW + hr * W + w;
    float hreg[CH];
    #pragma unroll
    for (int i = 0; i < CH; ++i) hreg[i] = hbase[(size_t)i * HW];
    float ck[MODES], sk[MODES];
    #pragma unroll
    for (int k = 0; k < MODES; ++k) {
        ck[k] = cWkw[k * W + w];        // per-lane, coalesced
        sk[k] = sWkw[k * W + w];
    }
    float acc[CH];
    #pragma unroll
    for (int o = 0; o < CH; ++o) acc[o] = wb[o];        // uniform -> s_load
    #pragma unroll
    for (int i = 0; i < CH; ++i) {
        float hv = hreg[i];
        const float* wt = wwT + i * CH;                  // uniform -> s_load
        #pragma unroll
        for (int o = 0; o < CH; ++o) acc[o] += hv * wt[o];
    }
    const float* Zb = Z + ((size_t)b * H + hr) * CH * KX * 2;
    const float scale = 2.0f / (float)HW;                // irfft2 1/(H*W), x2 for herm
    #pragma unroll
    for (int o = 0; o < CH; ++o) {
        const float* zo = Zb + o * KX * 2;               // uniform -> s_load
        float x1 = 0.5f * zo[0];                         // DC: Re only, coeff 1
        #pragma unroll
        for (int k = 1; k < MODES; ++k)
            x1 += zo[2 * k] * ck[k] - zo[2 * k + 1] * sk[k];
        float v = acc[o] + x1 * scale;
        hbase[(size_t)o * HW] = gelu_f(v);
    }
}

// ---------------- mean over H,W ---------------------------------------------
__global__ __launch_bounds__(256) void k_mean(
        const float* __restrict__ h, float* __restrict__ g) {
    int bc = blockIdx.x;                // b*CH + c
    int tid = threadIdx.x;
    const float4* src4 = (const float4*)(h + (size_t)bc * HW);
    float s = 0.f;
    for (int t = tid; t < HW / 4; t += 256) {
        float4 v = src4[t];
        s += v.x + v.y + v.z + v.w;
    }
    #pragma unroll
    for (int off = 32; off > 0; off >>= 1) s += __shfl_down(s, off, 64);
    __shared__ float red[4];
    if ((tid & 63) == 0) red[tid >> 6] = s;
    __syncthreads();
    if (tid == 0) g[bc] = (red[0] + red[1] + red[2] + red[3]) * (1.0f / (float)HW);
}

// ---------------- head MLP: 32 -> 128 gelu -> 1 -> sigmoid ------------------
__global__ __launch_bounds__(128) void k_head(
        const float* __restrict__ g, const float* __restrict__ q1w,
        const float* __restrict__ q1b, const float* __restrict__ q2w,
        const float* __restrict__ q2b, float* __restrict__ out) {
    __shared__ float gs[CH];
    __shared__ float red2[2];
    int b = blockIdx.x;
    int t = threadIdx.x;
    if (t < CH) gs[t] = g[b * CH + t];
    __syncthreads();
    float a = q1b[t];
    #pragma unroll
    for (int c = 0; c < CH; ++c) a += gs[c] * q1w[t * CH + c];
    a = gelu_f(a);
    float hsum = a * q2w[t];
    #pragma unroll
    for (int off = 32; off > 0; off >>= 1) hsum += __shfl_down(hsum, off, 64);
    if ((t & 63) == 0) red2[t >> 6] = hsum;
    __syncthreads();
    if (t == 0) {
        float logit = red2[0] + red2[1] + q2b[0];
        out[b] = 1.0f / (1.0f + expf(-logit));
    }
}

extern "C" void kernel_launch(void* const* d_in, const int* in_sizes, int n_in,
                              void* d_out, int out_size, void* d_ws, size_t ws_size,
                              hipStream_t stream) {
    const float* x   = (const float*)d_in[0];
    const float* p_w = (const float*)d_in[1];
    const float* p_b = (const float*)d_in[2];
    const float* w1r = (const float*)d_in[3];
    const float* w1i = (const float*)d_in[4];
    const float* w2r = (const float*)d_in[5];
    const float* w2i = (const float*)d_in[6];
    const float* ww  = (const float*)d_in[7];
    const float* wb  = (const float*)d_in[8];
    const float* q1w = (const float*)d_in[9];
    const float* q1b = (const float*)d_in[10];
    const float* q2w = (const float*)d_in[11];
    const float* q2b = (const float*)d_in[12];
    float* out = (float*)d_out;

    float* ws = (float*)d_ws;
    size_t off = 0;
    auto alloc = [&](size_t n) {
        float* p = ws + off;
        off += (n + 63) & ~(size_t)63;   // 256B-align
        return p;
    };
    float* cWwk = alloc(W * MODES);
    float* sWwk = alloc(W * MODES);
    float* cWkw = alloc(MODES * W);
    float* sWkw = alloc(MODES * W);
    float* cHhk = alloc(H * KY);
    float* sHhk = alloc(H * KY);
    float* cHkh = alloc(KY * H);
    float* sHkh = alloc(KY * H);
    float* hBuf = alloc((size_t)B * CH * HW);            // 134 MB
    float* XwZ  = alloc((size_t)B * CH * H * KX * 2);    // 25 MB (Xw, reused as Z)
    float* Xf   = alloc((size_t)NMODE * B * CH * 2);     // 4.7 MB
    float* Yf   = alloc((size_t)B * CH * NMODE * 2);     // 4.7 MB
    float* wR   = alloc((size_t)4 * NMODE * CH * CH * 2);// 9.4 MB
    float* wwT  = alloc(4 * CH * CH);
    float* g    = alloc(B * CH);

    // tables + weight layouts (recomputed every call: deterministic)
    k_init_tables<<<(MODES * W + KY * H + 255) / 256, 256, 0, stream>>>(
        cWwk, sWwk, cWkw, sWkw, cHhk, sHhk, cHkh, sHkh);
    k_reorder_w<<<(4 * NMODE * CH * CH + 255) / 256, 256, 0, stream>>>(
        w1r, w1i, w2r, w2i, wR);
    k_transpose_ww<<<(4 * CH * CH + 255) / 256, 256, 0, stream>>>(ww, wwT);

    k_lift<<<B * H, 128, 0, stream>>>(x, p_w, p_b, hBuf);

    for (int layer = 0; layer < 4; ++layer) {
        k_dft_w<<<(B * CH * H) / 256, 256, 0, stream>>>(hBuf, cWwk, sWwk, XwZ);
        k_dft_h<<<dim3((B * CH * KX) / 256, 2), 256, 0, stream>>>(XwZ, cHhk, sHhk, Xf);
        k_specmul<<<NMODE, 256, 0, stream>>>(
            Xf, wR + (size_t)layer * NMODE * CH * CH * 2, Yf);
        k_idft_h<<<B * CH, 128, 0, stream>>>(Yf, cHkh, sHkh, XwZ);
        k_fused<<<B * H, 128, 0, stream>>>(
            hBuf, XwZ, wwT + layer * CH * CH, wb + layer * CH, cWkw, sWkw);
    }

    k_mean<<<B * CH, 256, 0, stream>>>(hBuf, g);
    k_head<<<B, 128, 0, stream>>>(g, q1w, q1b, q2w, q2b, out);
}

// Round 2
// 2104.382 us; speedup vs baseline: 2.5736x; 2.5736x over previous
//
#include <hip/hip_runtime.h>
#include <math.h>

#define B 64
#define CIN 2
#define CH 32
#define H 128
#define W 128
#define MODES 12
#define KY 24              // kept ky rows: 0..11 and 116..127
#define KX 12              // kept kx cols
#define HW (H*W)           // 16384
#define NMODE (KY*KX)      // 288

__device__ __forceinline__ float gelu_f(float x) {
    return 0.5f * x * (1.0f + erff(x * 0.70710678118654752f));
}

// ---------------- twiddle tables ----------------
// W tables:  [w][k] (for s_load in dft_w)  and [k][w] (per-lane in fused irfft)
// H tables:  [h][ky] (s_load in dft_h/idft_h) and [ky][h] (unused-lane layout)
__global__ __launch_bounds__(256) void k_init_tables(
        float* cWwk, float* sWwk, float* cWkw, float* sWkw,
        float* cHhk, float* sHhk, float* cHkh, float* sHkh) {
    int t = blockIdx.x * 256 + threadIdx.x;
    const float TWO_PI_OVER = 6.283185307179586476925f / 128.0f;
    if (t < MODES * W) {
        int k = t / W, w = t % W;
        int m = (k * w) & 127;
        float s, c;
        sincosf(TWO_PI_OVER * (float)m, &s, &c);
        cWkw[k * W + w] = c;  sWkw[k * W + w] = s;
        cWwk[w * MODES + k] = c;  sWwk[w * MODES + k] = s;
    } else if (t < MODES * W + KY * H) {
        int u = t - MODES * W;
        int kyI = u / H, hh = u % H;
        int ky = (kyI < MODES) ? kyI : (H - MODES + (kyI - MODES));  // 116..127
        int m = (ky * hh) & 127;
        float s, c;
        sincosf(TWO_PI_OVER * (float)m, &s, &c);
        cHkh[kyI * H + hh] = c;  sHkh[kyI * H + hh] = s;
        cHhk[hh * KY + kyI] = c;  sHhk[hh * KY + kyI] = s;
    }
}

// ---------------- weight reorder: wR[layer][m][i][o]{re,im}, m = kyI*KX+kx ---
__global__ __launch_bounds__(256) void k_reorder_w(
        const float* __restrict__ w1r, const float* __restrict__ w1i,
        const float* __restrict__ w2r, const float* __restrict__ w2i,
        float* __restrict__ wR) {
    int idx = blockIdx.x * 256 + threadIdx.x;   // 4*288*1024
    if (idx >= 4 * NMODE * CH * CH) return;
    int o = idx & 31;
    int i = (idx >> 5) & 31;
    int m = (idx >> 10) % NMODE;
    int layer = idx / (NMODE * CH * CH);
    int kyI = m / KX, kx = m % KX;
    const float *sr, *si;
    int row;
    if (kyI < MODES) { sr = w1r; si = w1i; row = kyI; }
    else             { sr = w2r; si = w2i; row = kyI - MODES; }
    int src = ((layer * CH + i) * CH + o) * (MODES * MODES) + row * MODES + kx;
    wR[(size_t)idx * 2]     = sr[src];
    wR[(size_t)idx * 2 + 1] = si[src];
}

// ---------------- ww transpose: wwT[layer][i][o] = ww[layer][o][i] ----------
__global__ __launch_bounds__(256) void k_transpose_ww(
        const float* __restrict__ ww, float* __restrict__ wwT) {
    int idx = blockIdx.x * 256 + threadIdx.x;
    if (idx >= 4 * CH * CH) return;
    int l = idx / (CH * CH);
    int r = idx % (CH * CH);
    int i = r / CH, o = r % CH;
    wwT[idx] = ww[l * CH * CH + o * CH + i];
}

// ---------------- lifting conv3x3 circular: x[B,2,H,W] -> h[B,32,H,W] -------
__global__ __launch_bounds__(128) void k_lift(
        const float* __restrict__ x, const float* __restrict__ pw,
        const float* __restrict__ pb, float* __restrict__ h) {
    int bh = blockIdx.x;            // b*H + hr
    int b = bh >> 7, hr = bh & 127;
    int w = threadIdx.x;
    int wl = (w + W - 1) & (W - 1), wr2 = (w + 1) & (W - 1);
    float xv[CIN][3][3];
    #pragma unroll
    for (int ic = 0; ic < CIN; ++ic) {
        const float* xc = x + (size_t)(b * CIN + ic) * HW;
        #pragma unroll
        for (int r = 0; r < 3; ++r) {
            int hh = (hr + r - 1 + H) & (H - 1);
            const float* xr = xc + hh * W;
            xv[ic][r][0] = xr[wl];
            xv[ic][r][1] = xr[w];
            xv[ic][r][2] = xr[wr2];
        }
    }
    for (int o = 0; o < CH; ++o) {
        float acc = pb[o];                       // uniform -> s_load
        const float* wo = pw + o * CIN * 9;      // uniform
        #pragma unroll
        for (int ic = 0; ic < CIN; ++ic)
            #pragma unroll
            for (int r = 0; r < 3; ++r)
                #pragma unroll
                for (int c3 = 0; c3 < 3; ++c3)
                    acc += xv[ic][r][c3] * wo[ic * 9 + r * 3 + c3];
        h[(size_t)(b * CH + o) * HW + hr * W + w] = acc;
    }
}

// ---------------- DFT along W: h rows -> Xw[row][k]{re,im}, k=0..11 ---------
__global__ __launch_bounds__(256) void k_dft_w(
        const float* __restrict__ h, const float* __restrict__ cWwk,
        const float* __restrict__ sWwk, float* __restrict__ Xw) {
    int row = blockIdx.x * 256 + threadIdx.x;   // < B*CH*H = 262144
    const float* src = h + (size_t)row * W;
    float accr[MODES], acci[MODES];
    #pragma unroll
    for (int k = 0; k < MODES; ++k) { accr[k] = 0.f; acci[k] = 0.f; }
    for (int w4 = 0; w4 < W; w4 += 4) {
        float4 v = *(const float4*)(src + w4);
        #pragma unroll
        for (int j = 0; j < 4; ++j) {
            float xval = (j == 0) ? v.x : (j == 1) ? v.y : (j == 2) ? v.z : v.w;
            int w = w4 + j;
            const float* cw = cWwk + w * MODES;   // uniform -> s_load
            const float* sw = sWwk + w * MODES;
            #pragma unroll
            for (int k = 0; k < MODES; ++k) {
                accr[k] += xval * cw[k];
                acci[k] -= xval * sw[k];
            }
        }
    }
    float2* dst = (float2*)(Xw + (size_t)row * MODES * 2);
    #pragma unroll
    for (int k = 0; k < MODES; ++k) dst[k] = make_float2(accr[k], acci[k]);
}

// ---------------- DFT along H: Xw -> Xf[m][b*CH+c]{re,im} -------------------
__global__ __launch_bounds__(256) void k_dft_h(
        const float* __restrict__ Xw, const float* __restrict__ cHhk,
        const float* __restrict__ sHhk, float* __restrict__ Xf) {
    int t = blockIdx.x * 256 + threadIdx.x;     // < B*CH*KX = 24576
    int bc = t / KX, kx = t % KX;
    int kyh = blockIdx.y;                        // 0 or 1 -> ky block of 12
    const float2* src = (const float2*)Xw + (size_t)bc * H * KX + kx;
    float accr[MODES], acci[MODES];
    #pragma unroll
    for (int j = 0; j < MODES; ++j) { accr[j] = 0.f; acci[j] = 0.f; }
    for (int hh = 0; hh < H; ++hh) {
        float2 v = src[hh * KX];
        const float* ch = cHhk + hh * KY + kyh * MODES;  // uniform -> s_load
        const float* sh = sHhk + hh * KY + kyh * MODES;
        #pragma unroll
        for (int j = 0; j < MODES; ++j) {
            float c = ch[j], s = sh[j];
            accr[j] += v.x * c + v.y * s;   // (xr+ixi)(c-is)
            acci[j] += v.y * c - v.x * s;
        }
    }
    float2* dst = (float2*)Xf;
    #pragma unroll
    for (int j = 0; j < MODES; ++j) {
        int m = (kyh * MODES + j) * KX + kx;
        dst[(size_t)m * (B * CH) + bc] = make_float2(accr[j], acci[j]);
    }
}

// ---------------- spectral channel mix: per mode, Y[b,o] = sum_i X[b,i]W[i,o]
// Output layout Yt[b][m][o]{re,im} (o minor -> coalesced, feeds k_idft_h).
__global__ __launch_bounds__(256) void k_specmul(
        const float* __restrict__ Xf, const float* __restrict__ wRl,
        float* __restrict__ Yt) {
    int m = blockIdx.x;                 // 0..287
    int o = threadIdx.x & 31;
    int bq = threadIdx.x >> 5;          // 0..7 -> 8 b's each
    const float2* X  = (const float2*)Xf  + (size_t)m * (B * CH);
    const float2* Wm = (const float2*)wRl + (size_t)m * (CH * CH);
    float accr[8], acci[8];
    #pragma unroll
    for (int j = 0; j < 8; ++j) { accr[j] = 0.f; acci[j] = 0.f; }
    for (int i = 0; i < CH; ++i) {
        float2 wv = Wm[i * CH + o];     // coalesced across lanes
        #pragma unroll
        for (int j = 0; j < 8; ++j) {
            int b = bq * 8 + j;
            float2 xv = X[b * CH + i];  // shared across 32 lanes -> cache bcast
            accr[j] += xv.x * wv.x - xv.y * wv.y;
            acci[j] += xv.x * wv.y + xv.y * wv.x;
        }
    }
    float2* Yp = (float2*)Yt;
    #pragma unroll
    for (int j = 0; j < 8; ++j) {
        int b = bq * 8 + j;
        Yp[((size_t)b * NMODE + m) * CH + o] = make_float2(accr[j], acci[j]);
    }
}

// ---------------- inverse DFT along H: Yt -> Zt[b][h][p][kx][o], pre-scaled -
// thread = (o, kx); y-coeffs register-resident; twiddles uniform -> s_load.
// Zt re-plane scaled by (kx==0?1:2)/HW so k_fused just accumulates.
__global__ __launch_bounds__(384) void k_idft_h(
        const float* __restrict__ Yt, const float* __restrict__ cHhk,
        const float* __restrict__ sHhk, float* __restrict__ Zt) {
    int b = blockIdx.x;
    int hh0 = blockIdx.y * 16;           // 8 chunks of 16 rows
    int o = threadIdx.x & 31;
    int kx = threadIdx.x >> 5;           // 0..11
    float yr[KY], yi[KY];
    #pragma unroll
    for (int ky = 0; ky < KY; ++ky) {
        float2 v = ((const float2*)Yt)[((size_t)b * NMODE + ky * KX + kx) * CH + o];
        yr[ky] = v.x;  yi[ky] = v.y;
    }
    float sc = (kx == 0 ? 1.0f : 2.0f) / (float)HW;
    #pragma unroll 2
    for (int hr = 0; hr < 16; ++hr) {
        int hh = hh0 + hr;
        const float* c = cHhk + hh * KY;     // uniform -> s_load
        const float* s = sHhk + hh * KY;
        float re = 0.f, im = 0.f;
        #pragma unroll
        for (int ky = 0; ky < KY; ++ky) {
            re += yr[ky] * c[ky] - yi[ky] * s[ky];
            im += yr[ky] * s[ky] + yi[ky] * c[ky];
        }
        size_t base = ((size_t)(b * H + hh) * 2) * (KX * CH) + kx * CH + o;
        Zt[base]            = re * sc;
        Zt[base + KX * CH]  = im * sc;
    }
}

// ---------------- fused: pointwise GEMM + irfft(W) + bias + GELU, in-place h
// 256 thr per (b,row): LDS-staged h row (kills the in-place race), each wave
// owns 16 output channels; all weight/Z reads are 16-float uniform s_loads.
__global__ __launch_bounds__(256) void k_fused(
        float* __restrict__ h, const float* __restrict__ Zt,
        const float* __restrict__ wwT, const float* __restrict__ wb,
        const float* __restrict__ cWkw, const float* __restrict__ sWkw) {
    __shared__ float hs[CH * W];         // 16 KB
    int bh = blockIdx.x;                 // b*H + hr
    int b = bh >> 7, hr = bh & 127;
    int tid = threadIdx.x;
    int w = tid & 127;
    int oh = __builtin_amdgcn_readfirstlane(tid >> 7);   // wave-uniform 0/1
    const float* hrow = h + (size_t)b * CH * HW + hr * W;
    #pragma unroll
    for (int r = 0; r < 4; ++r) {        // stage 32x128 row into LDS
        int f4 = r * 256 + tid;          // float4 index, 0..1023
        int i = f4 >> 5;
        int col = (f4 & 31) * 4;
        float4 v = *(const float4*)(hrow + (size_t)i * HW + col);
        *(float4*)(hs + i * W + col) = v;
    }
    float ck[MODES], nsk[MODES];
    #pragma unroll
    for (int k = 0; k < MODES; ++k) {
        ck[k]  = cWkw[k * W + w];        // per-lane, coalesced, L1-hot
        nsk[k] = -sWkw[k * W + w];
    }
    float acc[16];
    const float* wbo = wb + oh * 16;     // uniform
    #pragma unroll
    for (int j = 0; j < 16; ++j) acc[j] = wbo[j];
    __syncthreads();
    // pointwise: acc[j] += sum_i hs[i][w] * wwT[i][oh*16+j]
    #pragma unroll 4
    for (int i = 0; i < CH; ++i) {
        float hv = hs[i * W + w];
        const float* wt = wwT + i * CH + oh * 16;        // uniform -> s_load x16
        #pragma unroll
        for (int j = 0; j < 16; ++j) acc[j] += hv * wt[j];
    }
    // spectral: acc[j] += sum_k zr[k][o]*ck[k] - zi[k][o]*sk[k]  (pre-scaled)
    const float* Zb = Zt + ((size_t)bh * 2) * (KX * CH) + oh * 16;
    #pragma unroll
    for (int k = 0; k < MODES; ++k) {
        const float* zr = Zb + k * CH;                   // uniform -> s_load x16
        const float* zi = zr + KX * CH;
        float ckv = ck[k], nskv = nsk[k];
        #pragma unroll
        for (int j = 0; j < 16; ++j)
            acc[j] += zr[j] * ckv + zi[j] * nskv;
    }
    float* hout = h + (size_t)(b * CH + oh * 16) * HW + hr * W + w;
    #pragma unroll
    for (int j = 0; j < 16; ++j)
        hout[(size_t)j * HW] = gelu_f(acc[j]);
}

// ---------------- mean over H,W ---------------------------------------------
__global__ __launch_bounds__(256) void k_mean(
        const float* __restrict__ h, float* __restrict__ g) {
    int bc = blockIdx.x;                // b*CH + c
    int tid = threadIdx.x;
    const float4* src4 = (const float4*)(h + (size_t)bc * HW);
    float s = 0.f;
    for (int t = tid; t < HW / 4; t += 256) {
        float4 v = src4[t];
        s += v.x + v.y + v.z + v.w;
    }
    #pragma unroll
    for (int off = 32; off > 0; off >>= 1) s += __shfl_down(s, off, 64);
    __shared__ float red[4];
    if ((tid & 63) == 0) red[tid >> 6] = s;
    __syncthreads();
    if (tid == 0) g[bc] = (red[0] + red[1] + red[2] + red[3]) * (1.0f / (float)HW);
}

// ---------------- head MLP: 32 -> 128 gelu -> 1 -> sigmoid ------------------
__global__ __launch_bounds__(128) void k_head(
        const float* __restrict__ g, const float* __restrict__ q1w,
        const float* __restrict__ q1b, const float* __restrict__ q2w,
        const float* __restrict__ q2b, float* __restrict__ out) {
    __shared__ float gs[CH];
    __shared__ float red2[2];
    int b = blockIdx.x;
    int t = threadIdx.x;
    if (t < CH) gs[t] = g[b * CH + t];
    __syncthreads();
    float a = q1b[t];
    #pragma unroll
    for (int c = 0; c < CH; ++c) a += gs[c] * q1w[t * CH + c];
    a = gelu_f(a);
    float hsum = a * q2w[t];
    #pragma unroll
    for (int off = 32; off > 0; off >>= 1) hsum += __shfl_down(hsum, off, 64);
    if ((t & 63) == 0) red2[t >> 6] = hsum;
    __syncthreads();
    if (t == 0) {
        float logit = red2[0] + red2[1] + q2b[0];
        out[b] = 1.0f / (1.0f + expf(-logit));
    }
}

extern "C" void kernel_launch(void* const* d_in, const int* in_sizes, int n_in,
                              void* d_out, int out_size, void* d_ws, size_t ws_size,
                              hipStream_t stream) {
    const float* x   = (const float*)d_in[0];
    const float* p_w = (const float*)d_in[1];
    const float* p_b = (const float*)d_in[2];
    const float* w1r = (const float*)d_in[3];
    const float* w1i = (const float*)d_in[4];
    const float* w2r = (const float*)d_in[5];
    const float* w2i = (const float*)d_in[6];
    const float* ww  = (const float*)d_in[7];
    const float* wb  = (const float*)d_in[8];
    const float* q1w = (const float*)d_in[9];
    const float* q1b = (const float*)d_in[10];
    const float* q2w = (const float*)d_in[11];
    const float* q2b = (const float*)d_in[12];
    float* out = (float*)d_out;

    float* ws = (float*)d_ws;
    size_t off = 0;
    auto alloc = [&](size_t n) {
        float* p = ws + off;
        off += (n + 63) & ~(size_t)63;   // 256B-align
        return p;
    };
    float* cWwk = alloc(W * MODES);
    float* sWwk = alloc(W * MODES);
    float* cWkw = alloc(MODES * W);
    float* sWkw = alloc(MODES * W);
    float* cHhk = alloc(H * KY);
    float* sHhk = alloc(H * KY);
    float* cHkh = alloc(KY * H);
    float* sHkh = alloc(KY * H);
    float* hBuf = alloc((size_t)B * CH * HW);            // 134 MB
    float* XwZ  = alloc((size_t)B * CH * H * KX * 2);    // 25 MB (Xw, reused as Zt)
    float* Xf   = alloc((size_t)NMODE * B * CH * 2);     // 4.7 MB
    float* Yt   = alloc((size_t)B * NMODE * CH * 2);     // 4.7 MB
    float* wR   = alloc((size_t)4 * NMODE * CH * CH * 2);// 9.4 MB
    float* wwT  = alloc(4 * CH * CH);
    float* g    = alloc(B * CH);

    // tables + weight layouts (recomputed every call: deterministic)
    k_init_tables<<<(MODES * W + KY * H + 255) / 256, 256, 0, stream>>>(
        cWwk, sWwk, cWkw, sWkw, cHhk, sHhk, cHkh, sHkh);
    k_reorder_w<<<(4 * NMODE * CH * CH + 255) / 256, 256, 0, stream>>>(
        w1r, w1i, w2r, w2i, wR);
    k_transpose_ww<<<(4 * CH * CH + 255) / 256, 256, 0, stream>>>(ww, wwT);

    k_lift<<<B * H, 128, 0, stream>>>(x, p_w, p_b, hBuf);

    for (int layer = 0; layer < 4; ++layer) {
        k_dft_w<<<(B * CH * H) / 256, 256, 0, stream>>>(hBuf, cWwk, sWwk, XwZ);
        k_dft_h<<<dim3((B * CH * KX) / 256, 2), 256, 0, stream>>>(XwZ, cHhk, sHhk, Xf);
        k_specmul<<<NMODE, 256, 0, stream>>>(
            Xf, wR + (size_t)layer * NMODE * CH * CH * 2, Yt);
        k_idft_h<<<dim3(B, 8), 384, 0, stream>>>(Yt, cHhk, sHhk, XwZ);
        k_fused<<<B * H, 256, 0, stream>>>(
            hBuf, XwZ, wwT + layer * CH * CH, wb + layer * CH, cWkw, sWkw);
    }

    k_mean<<<B * CH, 256, 0, stream>>>(hBuf, g);
    k_head<<<B, 128, 0, stream>>>(g, q1w, q1b, q2w, q2b, out);
}

// Round 3
// 1021.614 us; speedup vs baseline: 5.3013x; 2.0599x over previous
//
#include <hip/hip_runtime.h>
#include <math.h>

#define B 64
#define CIN 2
#define CH 32
#define H 128
#define W 128
#define MODES 12
#define KY 24              // kept ky rows: 0..11 and 116..127
#define KX 12              // kept kx cols
#define HW (H*W)           // 16384
#define NMODE (KY*KX)      // 288

// exact-erf GELU via Abramowitz-Stegun 7.1.26 (|erf err| < 1.5e-7), branch-free
__device__ __forceinline__ float gelu_f(float x) {
    float ax = fabsf(x) * 0.70710678118654752f;
    float t  = __builtin_amdgcn_rcpf(1.0f + 0.3275911f * ax);
    float p  = t * (0.254829592f + t * (-0.284496736f + t * (1.421413741f +
               t * (-1.453152027f + t * 1.061405429f))));
    float e  = __expf(-ax * ax);
    float er = copysignf(1.0f - p * e, x);
    return 0.5f * x * (1.0f + er);
}

// ---------------- twiddle tables ----------------
// W tables:  [w][k] (for s_load in dft_w)  and [k][w] (per-lane in fused irfft)
// H tables:  [h][ky] (s_load in dft_h/idft_h) and [ky][h] (spare layout)
__global__ __launch_bounds__(256) void k_init_tables(
        float* cWwk, float* sWwk, float* cWkw, float* sWkw,
        float* cHhk, float* sHhk, float* cHkh, float* sHkh) {
    int t = blockIdx.x * 256 + threadIdx.x;
    const float TWO_PI_OVER = 6.283185307179586476925f / 128.0f;
    if (t < MODES * W) {
        int k = t / W, w = t % W;
        int m = (k * w) & 127;
        float s, c;
        sincosf(TWO_PI_OVER * (float)m, &s, &c);
        cWkw[k * W + w] = c;  sWkw[k * W + w] = s;
        cWwk[w * MODES + k] = c;  sWwk[w * MODES + k] = s;
    } else if (t < MODES * W + KY * H) {
        int u = t - MODES * W;
        int kyI = u / H, hh = u % H;
        int ky = (kyI < MODES) ? kyI : (H - MODES + (kyI - MODES));  // 116..127
        int m = (ky * hh) & 127;
        float s, c;
        sincosf(TWO_PI_OVER * (float)m, &s, &c);
        cHkh[kyI * H + hh] = c;  sHkh[kyI * H + hh] = s;
        cHhk[hh * KY + kyI] = c;  sHhk[hh * KY + kyI] = s;
    }
}

// ---------------- weight reorder: wR[layer][m][i][o]{re,im}, m = kyI*KX+kx ---
__global__ __launch_bounds__(256) void k_reorder_w(
        const float* __restrict__ w1r, const float* __restrict__ w1i,
        const float* __restrict__ w2r, const float* __restrict__ w2i,
        float* __restrict__ wR) {
    int idx = blockIdx.x * 256 + threadIdx.x;   // 4*288*1024
    if (idx >= 4 * NMODE * CH * CH) return;
    int o = idx & 31;
    int i = (idx >> 5) & 31;
    int m = (idx >> 10) % NMODE;
    int layer = idx / (NMODE * CH * CH);
    int kyI = m / KX, kx = m % KX;
    const float *sr, *si;
    int row;
    if (kyI < MODES) { sr = w1r; si = w1i; row = kyI; }
    else             { sr = w2r; si = w2i; row = kyI - MODES; }
    int src = ((layer * CH + i) * CH + o) * (MODES * MODES) + row * MODES + kx;
    wR[(size_t)idx * 2]     = sr[src];
    wR[(size_t)idx * 2 + 1] = si[src];
}

// ---------------- ww transpose: wwT[layer][i][o] = ww[layer][o][i] ----------
__global__ __launch_bounds__(256) void k_transpose_ww(
        const float* __restrict__ ww, float* __restrict__ wwT) {
    int idx = blockIdx.x * 256 + threadIdx.x;
    if (idx >= 4 * CH * CH) return;
    int l = idx / (CH * CH);
    int r = idx % (CH * CH);
    int i = r / CH, o = r % CH;
    wwT[idx] = ww[l * CH * CH + o * CH + i];
}

// ---------------- lifting conv3x3 circular: x[B,2,H,W] -> h[B,32,H,W] -------
__global__ __launch_bounds__(128) void k_lift(
        const float* __restrict__ x, const float* __restrict__ pw,
        const float* __restrict__ pb, float* __restrict__ h) {
    int bh = blockIdx.x;            // b*H + hr
    int b = bh >> 7, hr = bh & 127;
    int w = threadIdx.x;
    int wl = (w + W - 1) & (W - 1), wr2 = (w + 1) & (W - 1);
    float xv[CIN][3][3];
    #pragma unroll
    for (int ic = 0; ic < CIN; ++ic) {
        const float* xc = x + (size_t)(b * CIN + ic) * HW;
        #pragma unroll
        for (int r = 0; r < 3; ++r) {
            int hh = (hr + r - 1 + H) & (H - 1);
            const float* xr = xc + hh * W;
            xv[ic][r][0] = xr[wl];
            xv[ic][r][1] = xr[w];
            xv[ic][r][2] = xr[wr2];
        }
    }
    for (int o = 0; o < CH; ++o) {
        float acc = pb[o];                       // uniform -> s_load
        const float* wo = pw + o * CIN * 9;      // uniform
        #pragma unroll
        for (int ic = 0; ic < CIN; ++ic)
            #pragma unroll
            for (int r = 0; r < 3; ++r)
                #pragma unroll
                for (int c3 = 0; c3 < 3; ++c3)
                    acc += xv[ic][r][c3] * wo[ic * 9 + r * 3 + c3];
        h[(size_t)(b * CH + o) * HW + hr * W + w] = acc;
    }
}

// ---------------- DFT along W: h rows -> Xw[row][k]{re,im}, k=0..11 ---------
__global__ __launch_bounds__(256) void k_dft_w(
        const float* __restrict__ h, const float* __restrict__ cWwk,
        const float* __restrict__ sWwk, float* __restrict__ Xw) {
    int row = blockIdx.x * 256 + threadIdx.x;   // < B*CH*H = 262144
    const float* src = h + (size_t)row * W;
    float accr[MODES], acci[MODES];
    #pragma unroll
    for (int k = 0; k < MODES; ++k) { accr[k] = 0.f; acci[k] = 0.f; }
    for (int w4 = 0; w4 < W; w4 += 4) {
        float4 v = *(const float4*)(src + w4);
        #pragma unroll
        for (int j = 0; j < 4; ++j) {
            float xval = (j == 0) ? v.x : (j == 1) ? v.y : (j == 2) ? v.z : v.w;
            int w = w4 + j;
            const float* cw = cWwk + w * MODES;   // uniform -> s_load
            const float* sw = sWwk + w * MODES;
            #pragma unroll
            for (int k = 0; k < MODES; ++k) {
                accr[k] += xval * cw[k];
                acci[k] -= xval * sw[k];
            }
        }
    }
    float2* dst = (float2*)(Xw + (size_t)row * MODES * 2);
    #pragma unroll
    for (int k = 0; k < MODES; ++k) dst[k] = make_float2(accr[k], acci[k]);
}

// ---------------- DFT along H: Xw -> Xf[m][b*CH+c]{re,im} -------------------
__global__ __launch_bounds__(256) void k_dft_h(
        const float* __restrict__ Xw, const float* __restrict__ cHhk,
        const float* __restrict__ sHhk, float* __restrict__ Xf) {
    int t = blockIdx.x * 256 + threadIdx.x;     // < B*CH*KX = 24576
    int bc = t / KX, kx = t % KX;
    int kyh = blockIdx.y;                        // 0 or 1 -> ky block of 12
    const float2* src = (const float2*)Xw + (size_t)bc * H * KX + kx;
    float accr[MODES], acci[MODES];
    #pragma unroll
    for (int j = 0; j < MODES; ++j) { accr[j] = 0.f; acci[j] = 0.f; }
    for (int hh = 0; hh < H; ++hh) {
        float2 v = src[hh * KX];
        const float* ch = cHhk + hh * KY + kyh * MODES;  // uniform -> s_load
        const float* sh = sHhk + hh * KY + kyh * MODES;
        #pragma unroll
        for (int j = 0; j < MODES; ++j) {
            float c = ch[j], s = sh[j];
            accr[j] += v.x * c + v.y * s;   // (xr+ixi)(c-is)
            acci[j] += v.y * c - v.x * s;
        }
    }
    float2* dst = (float2*)Xf;
    #pragma unroll
    for (int j = 0; j < MODES; ++j) {
        int m = (kyh * MODES + j) * KX + kx;
        dst[(size_t)m * (B * CH) + bc] = make_float2(accr[j], acci[j]);
    }
}

// ---------------- spectral channel mix: per mode, Y[b,o] = sum_i X[b,i]W[i,o]
// Output layout Yt[b][m][o]{re,im} (o minor -> coalesced, feeds k_idft_h).
__global__ __launch_bounds__(256) void k_specmul(
        const float* __restrict__ Xf, const float* __restrict__ wRl,
        float* __restrict__ Yt) {
    int m = blockIdx.x;                 // 0..287
    int o = threadIdx.x & 31;
    int bq = threadIdx.x >> 5;          // 0..7 -> 8 b's each
    const float2* X  = (const float2*)Xf  + (size_t)m * (B * CH);
    const float2* Wm = (const float2*)wRl + (size_t)m * (CH * CH);
    float accr[8], acci[8];
    #pragma unroll
    for (int j = 0; j < 8; ++j) { accr[j] = 0.f; acci[j] = 0.f; }
    for (int i = 0; i < CH; ++i) {
        float2 wv = Wm[i * CH + o];     // coalesced across lanes
        #pragma unroll
        for (int j = 0; j < 8; ++j) {
            int b = bq * 8 + j;
            float2 xv = X[b * CH + i];  // shared across 32 lanes -> cache bcast
            accr[j] += xv.x * wv.x - xv.y * wv.y;
            acci[j] += xv.x * wv.y + xv.y * wv.x;
        }
    }
    float2* Yp = (float2*)Yt;
    #pragma unroll
    for (int j = 0; j < 8; ++j) {
        int b = bq * 8 + j;
        Yp[((size_t)b * NMODE + m) * CH + o] = make_float2(accr[j], acci[j]);
    }
}

// ---------------- inverse DFT along H: Yt -> Zt[b][h][p][kx][o], pre-scaled -
// thread = (o, kx); y-coeffs register-resident; twiddles uniform -> s_load.
// Zt re-plane scaled by (kx==0?1:2)/HW so k_fused just accumulates.
__global__ __launch_bounds__(384) void k_idft_h(
        const float* __restrict__ Yt, const float* __restrict__ cHhk,
        const float* __restrict__ sHhk, float* __restrict__ Zt) {
    int b = blockIdx.x;
    int hh0 = blockIdx.y * 16;           // 8 chunks of 16 rows
    int o = threadIdx.x & 31;
    int kx = threadIdx.x >> 5;           // 0..11
    float yr[KY], yi[KY];
    #pragma unroll
    for (int ky = 0; ky < KY; ++ky) {
        float2 v = ((const float2*)Yt)[((size_t)b * NMODE + ky * KX + kx) * CH + o];
        yr[ky] = v.x;  yi[ky] = v.y;
    }
    float sc = (kx == 0 ? 1.0f : 2.0f) / (float)HW;
    #pragma unroll 2
    for (int hr = 0; hr < 16; ++hr) {
        int hh = hh0 + hr;
        const float* c = cHhk + hh * KY;     // uniform -> s_load
        const float* s = sHhk + hh * KY;
        float re = 0.f, im = 0.f;
        #pragma unroll
        for (int ky = 0; ky < KY; ++ky) {
            re += yr[ky] * c[ky] - yi[ky] * s[ky];
            im += yr[ky] * s[ky] + yi[ky] * c[ky];
        }
        size_t base = ((size_t)(b * H + hh) * 2) * (KX * CH) + kx * CH + o;
        Zt[base]            = re * sc;
        Zt[base + KX * CH]  = im * sc;
    }
}

// ---------------- fused: pointwise GEMM + irfft(W) + bias + GELU, in-place h
// 512 thr per (b,row); each thread owns 8 output channels (acc[8]+ck[12]+
// nsk[12] ~ 40 live VGPRs, no spill at the 128-VGPR cap from (512,4)).
// All weight/Z reads are 8-float wave-uniform s_loads.
__global__ __launch_bounds__(512, 4) void k_fused(
        float* __restrict__ h, const float* __restrict__ Zt,
        const float* __restrict__ wwT, const float* __restrict__ wb,
        const float* __restrict__ cWkw, const float* __restrict__ sWkw) {
    __shared__ float hs[CH * W];         // 16 KB
    int bh = blockIdx.x;                 // b*H + hr
    int b = bh >> 7, hr = bh & 127;
    int tid = threadIdx.x;
    int w = tid & 127;
    int og = __builtin_amdgcn_readfirstlane(tid >> 7);   // wave-uniform 0..3
    const float* hrow = h + (size_t)b * CH * HW + hr * W;
    #pragma unroll
    for (int r = 0; r < 2; ++r) {        // stage 32x128 row into LDS
        int f4 = r * 512 + tid;          // float4 index, 0..1023
        int i = f4 >> 5;
        int col = (f4 & 31) * 4;
        float4 v = *(const float4*)(hrow + (size_t)i * HW + col);
        *(float4*)(hs + i * W + col) = v;
    }
    float ck[MODES], nsk[MODES];
    #pragma unroll
    for (int k = 0; k < MODES; ++k) {
        ck[k]  = cWkw[k * W + w];        // per-lane, coalesced, L1-hot
        nsk[k] = -sWkw[k * W + w];
    }
    float acc[8];
    const float* wbo = wb + og * 8;      // uniform
    #pragma unroll
    for (int j = 0; j < 8; ++j) acc[j] = wbo[j];
    __syncthreads();
    // pointwise: acc[j] += sum_i hs[i][w] * wwT[i][og*8+j]
    #pragma unroll 4
    for (int i = 0; i < CH; ++i) {
        float hv = hs[i * W + w];
        const float* wt = wwT + i * CH + og * 8;         // uniform -> s_load x8
        #pragma unroll
        for (int j = 0; j < 8; ++j) acc[j] += hv * wt[j];
    }
    // spectral: acc[j] += sum_k zr[k][o]*ck[k] - zi[k][o]*sk[k]  (pre-scaled)
    const float* Zb = Zt + ((size_t)bh * 2) * (KX * CH) + og * 8;
    #pragma unroll
    for (int k = 0; k < MODES; ++k) {
        const float* zr = Zb + k * CH;                   // uniform -> s_load x8
        const float* zi = zr + KX * CH;
        float ckv = ck[k], nskv = nsk[k];
        #pragma unroll
        for (int j = 0; j < 8; ++j)
            acc[j] += zr[j] * ckv + zi[j] * nskv;
    }
    float* hout = h + (size_t)(b * CH + og * 8) * HW + hr * W + w;
    #pragma unroll
    for (int j = 0; j < 8; ++j)
        hout[(size_t)j * HW] = gelu_f(acc[j]);
}

// ---------------- mean over H,W ---------------------------------------------
__global__ __launch_bounds__(256) void k_mean(
        const float* __restrict__ h, float* __restrict__ g) {
    int bc = blockIdx.x;                // b*CH + c
    int tid = threadIdx.x;
    const float4* src4 = (const float4*)(h + (size_t)bc * HW);
    float s = 0.f;
    for (int t = tid; t < HW / 4; t += 256) {
        float4 v = src4[t];
        s += v.x + v.y + v.z + v.w;
    }
    #pragma unroll
    for (int off = 32; off > 0; off >>= 1) s += __shfl_down(s, off, 64);
    __shared__ float red[4];
    if ((tid & 63) == 0) red[tid >> 6] = s;
    __syncthreads();
    if (tid == 0) g[bc] = (red[0] + red[1] + red[2] + red[3]) * (1.0f / (float)HW);
}

// ---------------- head MLP: 32 -> 128 gelu -> 1 -> sigmoid ------------------
__global__ __launch_bounds__(128) void k_head(
        const float* __restrict__ g, const float* __restrict__ q1w,
        const float* __restrict__ q1b, const float* __restrict__ q2w,
        const float* __restrict__ q2b, float* __restrict__ out) {
    __shared__ float gs[CH];
    __shared__ float red2[2];
    int b = blockIdx.x;
    int t = threadIdx.x;
    if (t < CH) gs[t] = g[b * CH + t];
    __syncthreads();
    float a = q1b[t];
    #pragma unroll
    for (int c = 0; c < CH; ++c) a += gs[c] * q1w[t * CH + c];
    a = gelu_f(a);
    float hsum = a * q2w[t];
    #pragma unroll
    for (int off = 32; off > 0; off >>= 1) hsum += __shfl_down(hsum, off, 64);
    if ((t & 63) == 0) red2[t >> 6] = hsum;
    __syncthreads();
    if (t == 0) {
        float logit = red2[0] + red2[1] + q2b[0];
        out[b] = 1.0f / (1.0f + expf(-logit));
    }
}

extern "C" void kernel_launch(void* const* d_in, const int* in_sizes, int n_in,
                              void* d_out, int out_size, void* d_ws, size_t ws_size,
                              hipStream_t stream) {
    const float* x   = (const float*)d_in[0];
    const float* p_w = (const float*)d_in[1];
    const float* p_b = (const float*)d_in[2];
    const float* w1r = (const float*)d_in[3];
    const float* w1i = (const float*)d_in[4];
    const float* w2r = (const float*)d_in[5];
    const float* w2i = (const float*)d_in[6];
    const float* ww  = (const float*)d_in[7];
    const float* wb  = (const float*)d_in[8];
    const float* q1w = (const float*)d_in[9];
    const float* q1b = (const float*)d_in[10];
    const float* q2w = (const float*)d_in[11];
    const float* q2b = (const float*)d_in[12];
    float* out = (float*)d_out;

    float* ws = (float*)d_ws;
    size_t off = 0;
    auto alloc = [&](size_t n) {
        float* p = ws + off;
        off += (n + 63) & ~(size_t)63;   // 256B-align
        return p;
    };
    float* cWwk = alloc(W * MODES);
    float* sWwk = alloc(W * MODES);
    float* cWkw = alloc(MODES * W);
    float* sWkw = alloc(MODES * W);
    float* cHhk = alloc(H * KY);
    float* sHhk = alloc(H * KY);
    float* cHkh = alloc(KY * H);
    float* sHkh = alloc(KY * H);
    float* hBuf = alloc((size_t)B * CH * HW);            // 134 MB
    float* XwZ  = alloc((size_t)B * CH * H * KX * 2);    // 25 MB (Xw, reused as Zt)
    float* Xf   = alloc((size_t)NMODE * B * CH * 2);     // 4.7 MB
    float* Yt   = alloc((size_t)B * NMODE * CH * 2);     // 4.7 MB
    float* wR   = alloc((size_t)4 * NMODE * CH * CH * 2);// 9.4 MB
    float* wwT  = alloc(4 * CH * CH);
    float* g    = alloc(B * CH);

    // tables + weight layouts (recomputed every call: deterministic)
    k_init_tables<<<(MODES * W + KY * H + 255) / 256, 256, 0, stream>>>(
        cWwk, sWwk, cWkw, sWkw, cHhk, sHhk, cHkh, sHkh);
    k_reorder_w<<<(4 * NMODE * CH * CH + 255) / 256, 256, 0, stream>>>(
        w1r, w1i, w2r, w2i, wR);
    k_transpose_ww<<<(4 * CH * CH + 255) / 256, 256, 0, stream>>>(ww, wwT);

    k_lift<<<B * H, 128, 0, stream>>>(x, p_w, p_b, hBuf);

    for (int layer = 0; layer < 4; ++layer) {
        k_dft_w<<<(B * CH * H) / 256, 256, 0, stream>>>(hBuf, cWwk, sWwk, XwZ);
        k_dft_h<<<dim3((B * CH * KX) / 256, 2), 256, 0, stream>>>(XwZ, cHhk, sHhk, Xf);
        k_specmul<<<NMODE, 256, 0, stream>>>(
            Xf, wR + (size_t)layer * NMODE * CH * CH * 2, Yt);
        k_idft_h<<<dim3(B, 8), 384, 0, stream>>>(Yt, cHhk, sHhk, XwZ);
        k_fused<<<B * H, 512, 0, stream>>>(
            hBuf, XwZ, wwT + layer * CH * CH, wb + layer * CH, cWkw, sWkw);
    }

    k_mean<<<B * CH, 256, 0, stream>>>(hBuf, g);
    k_head<<<B, 128, 0, stream>>>(g, q1w, q1b, q2w, q2b, out);
}